// Round 3
// baseline (811.772 us; speedup 1.0000x reference)
//
#include <hip/hip_runtime.h>

// Problem constants (match reference setup_inputs / CUTOFF / N_IMAGES)
constexpr int M = 8;
constexpr int N = 400;
constexpr int K = 27;               // (2*N_IMAGES+1)^3
constexpr float CUT2 = 36.0f;       // CUTOFF^2
constexpr int D  = M * K * N * N;   // 34,560,000 elements per [M,K,N,N] output
constexpr int F4 = D / 4;           // 8,640,000 float4 units per such region
constexpr int ROW4 = (N * N) / 4;   // 40,000 float4 per (m,k) slab per region
constexpr int KG  = 3;              // k-groups in thread space
constexpr int KPT = K / KG;         // 9 k's per thread

typedef float f32x4 __attribute__((ext_vector_type(4)));

// ws layout (all 16B-aligned):
//   wrapped : float4[M*N]  (x,y,z,pad) at byte 0       (51200 B)
//   wo      : int4  [M*N]  (x,y,z,pad) at byte 51200   (51200 B)
//   shift   : float4[M*K]  (x,y,z,pad) at byte 102400  ( 3456 B)
constexpr int WS_WRAPPED = 0;
constexpr int WS_WO      = 51200;
constexpr int WS_SHIFT   = 102400;

__global__ __launch_bounds__(128)
void setup_kernel(const float* __restrict__ coords, const float* __restrict__ cell,
                  float4* __restrict__ wrapped, int4* __restrict__ wo,
                  float4* __restrict__ shift)
{
    int m = blockIdx.x;
    const float* c = cell + m * 9;
    float c00 = c[0], c01 = c[1], c02 = c[2];
    float c10 = c[3], c11 = c[4], c12 = c[5];
    float c20 = c[6], c21 = c[7], c22 = c[8];

    // 3x3 inverse via adjugate (cell is well-conditioned here)
    float det = c00 * (c11 * c22 - c12 * c21)
              - c01 * (c10 * c22 - c12 * c20)
              + c02 * (c10 * c21 - c11 * c20);
    float rd = 1.0f / det;
    float i00 = (c11 * c22 - c12 * c21) * rd, i01 = (c02 * c21 - c01 * c22) * rd, i02 = (c01 * c12 - c02 * c11) * rd;
    float i10 = (c12 * c20 - c10 * c22) * rd, i11 = (c00 * c22 - c02 * c20) * rd, i12 = (c02 * c10 - c00 * c12) * rd;
    float i20 = (c10 * c21 - c11 * c20) * rd, i21 = (c01 * c20 - c00 * c21) * rd, i22 = (c00 * c11 - c01 * c10) * rd;

    for (int n = threadIdx.x; n < N; n += blockDim.x) {
        int b = (m * N + n) * 3;
        float x = coords[b + 0], y = coords[b + 1], z = coords[b + 2];
        float p0 = x * i00 + y * i10 + z * i20;
        float p1 = x * i01 + y * i11 + z * i21;
        float p2 = x * i02 + y * i12 + z * i22;
        float f0 = floorf(p0), f1 = floorf(p1), f2 = floorf(p2);
        float4 wv;
        wv.x = x - (f0 * c00 + f1 * c10 + f2 * c20);
        wv.y = y - (f0 * c01 + f1 * c11 + f2 * c21);
        wv.z = z - (f0 * c02 + f1 * c12 + f2 * c22);
        wv.w = 0.0f;
        wrapped[m * N + n] = wv;
        int4 ov;
        ov.x = (int)f0; ov.y = (int)f1; ov.z = (int)f2; ov.w = 0;
        wo[m * N + n] = ov;
    }

    if (threadIdx.x < K) {
        int k = threadIdx.x;
        float fx = (float)(k / 9 - 1);
        float fy = (float)((k / 3) % 3 - 1);
        float fz = (float)(k % 3 - 1);
        float4 sv;
        sv.x = fx * c00 + fy * c10 + fz * c20;
        sv.y = fx * c01 + fy * c11 + fz * c21;
        sv.z = fx * c02 + fy * c12 + fz * c22;
        sv.w = 0.0f;
        shift[m * K + k] = sv;
    }
}

// k-coarsened pairs: each thread handles one (m, i, j-quad) for 9 consecutive
// k values. 15,000 long-lived waves (54 stores each) instead of 135,000
// short-lived ones -- fill-like store streaming, loads/index-math amortized 9x.
__global__ __launch_bounds__(128)
void pairs_kernel(const float4* __restrict__ wrapped, const int4* __restrict__ wo,
                  const float4* __restrict__ shift, float* __restrict__ out)
{
    // Wave-local transpose buffer (2 waves/block). Padded to 129 so the
    // read phase spreads bank-quads like the proven [3][257] layout.
    __shared__ f32x4 lds[3][129];

    int tid = threadIdx.x;
    int u = blockIdx.x * 128 + tid;        // [0, M*KG*N*(N/4)) = [0, 960,000)
    int jq = u % 100;
    int rest = u / 100;
    int i = rest % 400;
    int rest2 = rest / 400;                // [0, 24)
    int kg = rest2 % 3;
    int m  = rest2 / 3;
    int j0 = 4 * jq;

    const float4* wrow = wrapped + m * N;
    const int4*   orow = wo      + m * N;

    float4 wj[4]; int4 oj[4];
    #pragma unroll
    for (int dj = 0; dj < 4; ++dj) { wj[dj] = wrow[j0 + dj]; oj[dj] = orow[j0 + dj]; }
    float4 wi = wrow[i];
    int4   oi = orow[i];

    // k-invariant per-pair precomputation.
    // dx = wi - wj with the same __fsub_rn the reference association uses;
    // per k, px = __fadd_rn(dx, sh.x) is bit-identical to the 2-op original.
    float dx[4], dy[4], dz[4];
    int offd[4];
    bool excl[4];
    #pragma unroll
    for (int dj = 0; dj < 4; ++dj) {
        dx[dj] = __fsub_rn(wi.x, wj[dj].x);
        dy[dj] = __fsub_rn(wi.y, wj[dj].y);
        dz[dj] = __fsub_rn(wi.z, wj[dj].z);
        // offset_index = k - (dwz + 3*dwy + 9*dwx)  (base-3 digit identity)
        offd[dj] = (oi.z - oj[dj].z) + 3 * (oi.y - oj[dj].y) + 9 * (oi.x - oj[dj].x);
        excl[dj] = (kg == 1) && (i == j0 + dj);   // k==13 occurs at kg==1, kk==4
    }

    int k0 = kg * KPT;
    int mkbase = m * K + k0;
    int tbase = (mkbase * N + i) * 100 + jq;   // max 8,639,999 < 2^31

    int w64 = tid & ~63;
    int l   = tid & 63;
    int s2v[3], qv[3];
    #pragma unroll
    for (int rr = 0; rr < 3; ++rr) {
        int idx = rr * 64 + l;
        s2v[rr] = idx / 3;
        qv[rr]  = idx - 3 * s2v[rr];
    }

    f32x4* out4 = reinterpret_cast<f32x4*>(out);

    #pragma unroll
    for (int kk = 0; kk < KPT; ++kk) {
        float4 sh = shift[mkbase + kk];
        int t = tbase + kk * ROW4;
        int kcur = k0 + kk;

        float dist[4], msk[4], offv[4], pc[12];
        #pragma unroll
        for (int dj = 0; dj < 4; ++dj) {
            float px = __fadd_rn(dx[dj], sh.x);
            float py = __fadd_rn(dy[dj], sh.y);
            float pz = __fadd_rn(dz[dj], sh.z);
            float d2 = __fadd_rn(__fadd_rn(__fmul_rn(px, px), __fmul_rn(py, py)),
                                 __fmul_rn(pz, pz));
            bool mb = (d2 < CUT2);
            if (kk == 4) mb = mb && !excl[dj];
            dist[dj] = mb ? sqrtf(d2) : 0.0f;
            msk[dj]  = mb ? 1.0f : 0.0f;
            pc[3 * dj + 0] = mb ? px : 0.0f;
            pc[3 * dj + 1] = mb ? py : 0.0f;
            pc[3 * dj + 2] = mb ? pz : 0.0f;
            offv[dj] = (float)(kcur - offd[dj]);
        }

        f32x4 dv = { dist[0], dist[1], dist[2], dist[3] };
        f32x4 mv = { msk[0],  msk[1],  msk[2],  msk[3]  };
        f32x4 ov = { offv[0], offv[1], offv[2], offv[3] };
        out4[t]          = dv;
        out4[4 * F4 + t] = mv;
        out4[5 * F4 + t] = ov;

        // paircoord via wave-local LDS transpose (same scheme as R1/R2,
        // proven correct): wave's dest range = [F4 + 3*(t-l), +192)
        f32x4 p0 = { pc[0], pc[1], pc[2],  pc[3]  };
        f32x4 p1 = { pc[4], pc[5], pc[6],  pc[7]  };
        f32x4 p2 = { pc[8], pc[9], pc[10], pc[11] };
        lds[0][tid] = p0;
        lds[1][tid] = p1;
        lds[2][tid] = p2;
        __builtin_amdgcn_wave_barrier();   // order ds_writes before ds_reads
        int base = F4 + 3 * (t - l);
        #pragma unroll
        for (int rr = 0; rr < 3; ++rr) {
            out4[base + rr * 64 + l] = lds[qv[rr]][w64 + s2v[rr]];
        }
        __builtin_amdgcn_wave_barrier();   // order ds_reads before next-iter writes
    }
}

extern "C" void kernel_launch(void* const* d_in, const int* in_sizes, int n_in,
                              void* d_out, int out_size, void* d_ws, size_t ws_size,
                              hipStream_t stream) {
    const float* coords = (const float*)d_in[0];   // [M,N,3]
    const float* cell   = (const float*)d_in[1];   // [M,3,3]
    float* out = (float*)d_out;

    char* ws = (char*)d_ws;
    float4* wrapped = (float4*)(ws + WS_WRAPPED);
    int4*   wo      = (int4*)  (ws + WS_WO);
    float4* shift   = (float4*)(ws + WS_SHIFT);

    setup_kernel<<<M, 128, 0, stream>>>(coords, cell, wrapped, wo, shift);

    int total = M * KG * N * (N / 4);          // 960,000 threads
    int blocks = total / 128;                  // 7,500 exactly
    pairs_kernel<<<blocks, 128, 0, stream>>>(wrapped, wo, shift, out);
}